// Round 3
// 350.346 us; speedup vs baseline: 1.0198x; 1.0198x over previous
//
#include <hip/hip_runtime.h>
#include <math.h>

// power[b,t,d] = b_mag_d^2 * |S|^2,  S[t] = r_d*S[t-1] + x[b,t],
// r_d = e^{-softplus(alpha_raw_d)} * e^{i*omega_d}.  b_phase cancels in |H|^2.
// Chunked over t with K-step warm-up from zero state == reference's
// K-truncated FIR up to ~1e-5 amplitude terms.
//
// R4 = R2 with the compile fix: __builtin_nontemporal_store requires a native
// clang vector type, not HIP's float4 class. Structure unchanged:
//  (a) 256-thread blocks, 400-t chunk as TWO 200-output sub-chunks (own
//      K-step warm-up) -> 1600 blocks, ~25 waves/CU.
//  (b) LDS-transpose epilogue: per 4 steps each thread writes 4 powers to a
//      double-buffered LDS tile, one barrier, reads back a float4 and issues
//      ONE nontemporal global_store_dwordx4 (1 KB/wave-inst vs 4 x 256 B).

#define BB 8
#define LL 80000
#define DD 128
#define CHUNK 400         // per-block t coverage; CHUNK * NCHUNK == LL
#define SUB 200           // outputs per sub-chunk (multiple of 4)
#define NCHUNK 200
#define KMAX 1152         // multiple of 4
#define NT 256
#define GMAIN (SUB / 4)   // 50 float4 groups per sub-chunk

typedef __attribute__((ext_vector_type(4))) float f4;  // native vec for NT store

#define STEP(xv)                                   \
    {                                              \
        float t1 = fmaf(-ei, si, (xv));            \
        float nr = fmaf(er, sr, t1);               \
        float ni = fmaf(er, si, ei * sr);          \
        sr = nr; si = ni;                          \
    }

// One main group: 4 recurrence steps -> 4 powers -> LDS transpose ->
// one float4 nontemporal store. Double-buffered tile: single barrier/group.
#define GROUP_BODY(qq)                                                   \
    {                                                                    \
        float p0, p1, p2, p3;                                            \
        STEP(cur.x) p0 = scale * fmaf(sr, sr, si * si);                  \
        STEP(cur.y) p1 = scale * fmaf(sr, sr, si * si);                  \
        STEP(cur.z) p2 = scale * fmaf(sr, sr, si * si);                  \
        STEP(cur.w) p3 = scale * fmaf(sr, sr, si * si);                  \
        float* tw = &tb[(qq) & 1][sub * 512 + d];                        \
        tw[0] = p0; tw[128] = p1; tw[256] = p2; tw[384] = p3;            \
        __syncthreads();                                                 \
        const f4 v = *(const f4*)&tb[(qq) & 1][4 * tid];                 \
        __builtin_nontemporal_store(v, op4 + slot);                      \
        op4 += 128;                                                      \
    }

__global__ __launch_bounds__(NT) void sstfr_kernel(
    const float* __restrict__ x,          // (B, L)
    const float* __restrict__ omega,      // (D,)
    const float* __restrict__ alpha_raw,  // (D,)
    const float* __restrict__ b_log_mag,  // (D,)
    const int*   __restrict__ Kp,         // scalar
    float*       __restrict__ out)        // (B, L, D)
{
    __shared__ __align__(16) float xs[KMAX + CHUNK];
    __shared__ __align__(16) float tb[2][4 * NT];  // 2 x 4 KB transpose tiles

    const int tid  = threadIdx.x;          // 0..255
    const int d    = tid & (DD - 1);       // channel, 0..127
    const int sub  = tid >> 7;             // sub-chunk 0 or 1
    const int chunk = blockIdx.x;          // 0..NCHUNK-1
    const int b     = blockIdx.y;          // 0..B-1

    int K = Kp[0];
    K = (K + 3) & ~3;                      // float4 granularity
    if (K > KMAX) K = KMAX;                // deterministic K=1152; clamp safety

    const int t0    = chunk * CHUNK;
    const int base  = t0 - K;              // first staged x index (may be < 0)
    const int total = CHUNK + K;
    const float* xb = x + (size_t)b * LL;

    // Stage x window [t0-K, t0+CHUNK) into LDS (zero-pad left edge).
    for (int i = tid; i < total; i += NT) {
        const int idx = base + i;
        xs[i] = (idx >= 0 && idx < LL) ? xb[idx] : 0.0f;
    }
    __syncthreads();

    // Per-channel filter parameters.
    const float w     = omega[d];
    const float alpha = -log1pf(expf(alpha_raw[d]));   // -softplus
    const float ea    = expf(alpha);
    const float er    = ea * cosf(w);
    const float ei    = ea * sinf(w);
    const float scale = expf(2.0f * b_log_mag[d]);     // b_mag^2

    float sr = 0.0f, si = 0.0f;

    // Sub-chunk outputs [t0 + sub*SUB, +SUB); its warm-up starts K earlier,
    // i.e. at xs float4 offset sub*(SUB/4).
    const float4* x4 = (const float4*)xs + sub * (SUB / 4);
    const int g0 = K >> 2;                 // warm-up groups (288)

    float4 cur = x4[0];

    // Warm-up: prefetch next group before consuming current.
    for (int q = 0; q < g0; ++q) {
        float4 nxt = x4[q + 1];            // abs idx <= 338 < 388: in bounds
        STEP(cur.x) STEP(cur.y) STEP(cur.z) STEP(cur.w)
        cur = nxt;
    }

    // Output region for this sub-chunk; thread's float4 slot within each
    // 4t x 128d (2 KB) tile is tid&127 (transpose makes it linear).
    f4* op4 = (f4*)(out + ((size_t)b * LL + t0 + sub * SUB) * DD);
    const int slot = tid & 127;

    // Main: 49 groups with one-ahead prefetch, then peeled last group.
    for (int q = 0; q < GMAIN - 1; ++q) {
        float4 nxt = x4[g0 + q + 1];       // abs idx <= 387: in bounds
        GROUP_BODY(q)
        cur = nxt;
    }
    GROUP_BODY(GMAIN - 1)
}

extern "C" void kernel_launch(void* const* d_in, const int* in_sizes, int n_in,
                              void* d_out, int out_size, void* d_ws, size_t ws_size,
                              hipStream_t stream) {
    const float* x         = (const float*)d_in[0];
    const float* omega     = (const float*)d_in[1];
    const float* alpha_raw = (const float*)d_in[2];
    const float* b_log_mag = (const float*)d_in[3];
    // d_in[4] = b_phase: unused (cancels in |H|^2)
    const int*   Kp        = (const int*)d_in[5];
    float* out = (float*)d_out;

    dim3 grid(NCHUNK, BB);
    dim3 block(NT);
    sstfr_kernel<<<grid, block, 0, stream>>>(x, omega, alpha_raw, b_log_mag, Kp, out);
}